// Round 1
// baseline (172.930 us; speedup 1.0000x reference)
//
#include <hip/hip_runtime.h>
#include <stdint.h>

#define NPTS   131072
#define DEMB   512
#define NCL    512
#define BM     64
#define BK     64
#define NCHUNK (DEMB / BK)          // 8
#define NTHREADS 512
#define NBLK   (NPTS / BM)          // 2048

typedef __attribute__((ext_vector_type(4))) float f32x4;
typedef __attribute__((ext_vector_type(8))) short short8;

// ---- workspace layout (bytes) ----
// [0, 512KB)        : bf16 centroids, 8 chunks of 64KB, pre-swizzled LDS images
// [512KB, +2KB)     : c2[k] = ||c_k||^2 (f32)
// [514KB, +8KB)     : per-block partial sums (f32)
#define WS_CB   0u
#define WS_C2   (8u * 65536u)
#define WS_PART (WS_C2 + 2048u)

static __device__ __forceinline__ unsigned short f2bf(float f) {
  union { float f; uint32_t u; } c{f};
  uint32_t r = c.u + 0x7FFFu + ((c.u >> 16) & 1u);   // round-to-nearest-even
  return (unsigned short)(r >> 16);
}

typedef const __attribute__((address_space(1))) void gvoid;
typedef __attribute__((address_space(3))) void svoid;
static __device__ __forceinline__ void llds16(const void* g, void* s) {
  __builtin_amdgcn_global_load_lds((gvoid*)g, (svoid*)s, 16, 0, 0);
}

// ---------- prep: c2 + bf16-convert centroids into pre-swizzled chunk images ----------
__global__ __launch_bounds__(128) void prep_kernel(const float* __restrict__ cent,
                                                   uint8_t* __restrict__ ws) {
  const int k = blockIdx.x;
  const int t = threadIdx.x;
  float4 v = ((const float4*)(cent + (size_t)k * DEMB))[t];
  float sq = v.x * v.x + v.y * v.y + v.z * v.z + v.w * v.w;
#pragma unroll
  for (int m = 1; m < 64; m <<= 1) sq += __shfl_xor(sq, m, 64);
  __shared__ float red[2];
  if ((t & 63) == 0) red[t >> 6] = sq;
  __syncthreads();
  if (t == 0) ((float*)(ws + WS_C2))[k] = red[0] + red[1];

  ushort4 b;
  b.x = f2bf(v.x); b.y = f2bf(v.y); b.z = f2bf(v.z); b.w = f2bf(v.w);
  const int d = t * 4;
  const int chunk = d >> 6;
  const int dd = d & 63;
  const int slot = dd >> 3;            // 16B slot within 128B row
  const int within = (dd & 7) * 2;
  const uint32_t off = (uint32_t)chunk * 65536u + (uint32_t)k * 128u +
                       (uint32_t)(((slot ^ (k & 7)) << 4) + within);
  *(ushort4*)(ws + WS_CB + off) = b;
}

// ---------- fused GEMM + softmin epilogue ----------
__global__ __launch_bounds__(NTHREADS, 4) void main_kernel(
    const float* __restrict__ emb, const uint8_t* __restrict__ ws,
    const float* __restrict__ alphap) {
  extern __shared__ uint8_t smem[];
  uint8_t* cs = smem;              // 64KB: [512 clusters][64 d] bf16, XOR-swizzled
  uint8_t* xs = smem + 65536;      // 8KB : [64 rows][64 d]  bf16, XOR-swizzled
  // epilogue arrays alias cs (dead after last MFMA + barrier)
  float* redmin = (float*)smem;            // [8][64]
  float* gmin   = (float*)(smem + 2048);   // [64]
  float* redse  = (float*)(smem + 4096);   // [8][64]
  float* redsge = (float*)(smem + 6144);   // [8][64]
  float* x2s    = (float*)(smem + 8192);   // [64]
  float* vals   = (float*)(smem + 8448);   // [64]

  const int t = threadIdx.x;
  const int w = t >> 6;            // wave 0..7 -> clusters [64w, 64w+64)
  const int l = t & 63;
  const int l15 = l & 15;
  const int lhi = l >> 4;          // 0..3
  const int bid = blockIdx.x;
  const size_t row0 = (size_t)bid * BM;

  const float alpha = alphap[0];
  const float* c2g = (const float*)(ws + WS_C2);
  float* partials = (float*)(ws + WS_PART);

  float c2r[4];
#pragma unroll
  for (int n = 0; n < 4; ++n) c2r[n] = c2g[w * 64 + n * 16 + l15];

  f32x4 acc[4][4];
#pragma unroll
  for (int m = 0; m < 4; ++m)
#pragma unroll
    for (int n = 0; n < 4; ++n) acc[m][n] = (f32x4){0.f, 0.f, 0.f, 0.f};

  float x2a0 = 0.f, x2a1 = 0.f;

  for (int ch = 0; ch < NCHUNK; ++ch) {
    // stage centroid chunk: pre-swizzled bf16 image -> LDS via global_load_lds
    {
      const uint8_t* src =
          ws + WS_CB + (uint32_t)ch * 65536u + (uint32_t)w * 8192u + (uint32_t)l * 16u;
      uint8_t* dst = cs + w * 8192;
#pragma unroll
      for (int i = 0; i < 8; ++i) llds16(src + i * 1024, dst + i * 1024);
    }
    // stage x chunk: f32 -> bf16 swizzled; accumulate ||x||^2 in f32
    {
      const int d0 = ch * BK;
#pragma unroll
      for (int j = 0; j < 2; ++j) {
        const int f = t + j * 512;
        const int r = f >> 4;
        const int c4 = f & 15;
        float4 v = *(const float4*)(emb + (row0 + r) * DEMB + d0 + c4 * 4);
        float sq = v.x * v.x + v.y * v.y + v.z * v.z + v.w * v.w;
        if (j == 0) x2a0 += sq; else x2a1 += sq;
        ushort4 b;
        b.x = f2bf(v.x); b.y = f2bf(v.y); b.z = f2bf(v.z); b.w = f2bf(v.w);
        const int slot = c4 >> 1, within = (c4 & 1) * 8;
        *(ushort4*)(xs + r * 128 + (((slot ^ (r & 7)) << 4) + within)) = b;
      }
    }
    __syncthreads();
#pragma unroll
    for (int kk = 0; kk < 2; ++kk) {
      const int slot = kk * 4 + lhi;   // 16B slot 0..7
      short8 af[4], bfr[4];
#pragma unroll
      for (int m = 0; m < 4; ++m) {
        const int r = m * 16 + l15;
        af[m] = *(const short8*)(xs + r * 128 + ((slot ^ (r & 7)) << 4));
      }
#pragma unroll
      for (int n = 0; n < 4; ++n) {
        const int kc = w * 64 + n * 16 + l15;
        bfr[n] = *(const short8*)(cs + kc * 128 + ((slot ^ (kc & 7)) << 4));
      }
#pragma unroll
      for (int m = 0; m < 4; ++m)
#pragma unroll
        for (int n = 0; n < 4; ++n)
          acc[m][n] = __builtin_amdgcn_mfma_f32_16x16x32_bf16(af[m], bfr[n], acc[m][n], 0, 0, 0);
    }
    __syncthreads();
  }

  // ---- epilogue: g = c2 - 2*s ; val_row = min + sum((g-m)e)/sum(e) + x2 ----
#pragma unroll
  for (int m = 1; m < 16; m <<= 1) {
    x2a0 += __shfl_xor(x2a0, m, 64);
    x2a1 += __shfl_xor(x2a1, m, 64);
  }
  if ((t & 15) == 0) {
    x2s[t >> 4] = x2a0;
    x2s[32 + (t >> 4)] = x2a1;
  }

  float rmin[4][4];
#pragma unroll
  for (int m = 0; m < 4; ++m)
#pragma unroll
    for (int i = 0; i < 4; ++i) {
      float mn = c2r[0] - 2.f * acc[m][0][i];
#pragma unroll
      for (int n = 1; n < 4; ++n) mn = fminf(mn, c2r[n] - 2.f * acc[m][n][i]);
      rmin[m][i] = mn;
    }
#pragma unroll
  for (int msk = 1; msk < 16; msk <<= 1)
#pragma unroll
    for (int m = 0; m < 4; ++m)
#pragma unroll
      for (int i = 0; i < 4; ++i)
        rmin[m][i] = fminf(rmin[m][i], __shfl_xor(rmin[m][i], msk, 64));
  if (l15 == 0) {
#pragma unroll
    for (int m = 0; m < 4; ++m)
#pragma unroll
      for (int i = 0; i < 4; ++i)
        redmin[w * 64 + m * 16 + lhi * 4 + i] = rmin[m][i];
  }
  __syncthreads();
  if (t < 64) {
    float mn = redmin[t];
#pragma unroll
    for (int w2 = 1; w2 < 8; ++w2) mn = fminf(mn, redmin[w2 * 64 + t]);
    gmin[t] = mn;
  }
  __syncthreads();
#pragma unroll
  for (int m = 0; m < 4; ++m) {
#pragma unroll
    for (int i = 0; i < 4; ++i) {
      const int row = m * 16 + lhi * 4 + i;
      const float M = gmin[row];
      float se = 0.f, sge = 0.f;
#pragma unroll
      for (int n = 0; n < 4; ++n) {
        const float g = c2r[n] - 2.f * acc[m][n][i];
        const float gm = g - M;
        const float e = __expf(-alpha * gm);
        se += e;
        sge += gm * e;
      }
#pragma unroll
      for (int msk = 1; msk < 16; msk <<= 1) {
        se += __shfl_xor(se, msk, 64);
        sge += __shfl_xor(sge, msk, 64);
      }
      if (l15 == 0) {
        redse[w * 64 + row] = se;
        redsge[w * 64 + row] = sge;
      }
    }
  }
  __syncthreads();
  if (t < 64) {
    float Se = 0.f, Sge = 0.f;
#pragma unroll
    for (int w2 = 0; w2 < 8; ++w2) {
      Se += redse[w2 * 64 + t];
      Sge += redsge[w2 * 64 + t];
    }
    vals[t] = gmin[t] + Sge / Se + x2s[t];
  }
  __syncthreads();
  if (t < 64) {
    float v = vals[t];
#pragma unroll
    for (int msk = 1; msk < 64; msk <<= 1) v += __shfl_xor(v, msk, 64);
    if (t == 0) partials[bid] = v;
  }
}

// ---------- final deterministic reduction ----------
__global__ __launch_bounds__(256) void final_kernel(const uint8_t* __restrict__ ws,
                                                    const float* __restrict__ lambdp,
                                                    float* __restrict__ out) {
  const float* partials = (const float*)(ws + WS_PART);
  const int t = threadIdx.x;
  float s = 0.f;
  for (int i = t; i < NBLK; i += 256) s += partials[i];
#pragma unroll
  for (int msk = 1; msk < 64; msk <<= 1) s += __shfl_xor(s, msk, 64);
  __shared__ float red[4];
  if ((t & 63) == 0) red[t >> 6] = s;
  __syncthreads();
  if (t == 0)
    out[0] = lambdp[0] * (red[0] + red[1] + red[2] + red[3]) * (1.0f / (float)NPTS);
}

extern "C" void kernel_launch(void* const* d_in, const int* in_sizes, int n_in,
                              void* d_out, int out_size, void* d_ws, size_t ws_size,
                              hipStream_t stream) {
  const float* emb = (const float*)d_in[0];
  const float* cent = (const float*)d_in[1];
  const float* alphap = (const float*)d_in[2];
  const float* lambdp = (const float*)d_in[3];
  float* out = (float*)d_out;
  uint8_t* ws = (uint8_t*)d_ws;

  (void)hipFuncSetAttribute((const void*)main_kernel,
                            hipFuncAttributeMaxDynamicSharedMemorySize, 73728);

  prep_kernel<<<NCL, 128, 0, stream>>>(cent, ws);
  main_kernel<<<NBLK, NTHREADS, 73728, stream>>>(emb, ws, alphap);
  final_kernel<<<1, 256, 0, stream>>>(ws, lambdp, out);
}